// Round 5
// baseline (378.419 us; speedup 1.0000x reference)
//
#include <hip/hip_runtime.h>
#include <hip/hip_fp16.h>

// Problem constants
#define NN    256   // NUM_NODES
#define SS    4     // NUM_FSM_STATES
#define TT    3     // NUM_EDGE_TYPES
#define VV    4     // NUM_VARIANTS
#define NTY   8     // NUM_NODE_TYPES
#define NAC   15    // n_actions = T*S + 3
#define CAPG  48    // max packed pair-groups per col (96 edges; deg~Poi(38.4))
#define CAPE  (CAPG * 2)
#define ROWB  40    // bytes per tmp row (12 halves used + pad)
#define ZROWB (NN * ROWB)       // zero pad row byte offset = 10240 (fits u16)
#define BUFB  (ZROWB + ROWB)    // bytes per tmp buffer
#define ZPK   ((unsigned)ZROWB | ((unsigned)ZROWB << 16))
#define GMAXR 32    // groups held in registers (covers wave-max ~27; tail via global)

typedef _Float16 h2v __attribute__((ext_vector_type(2)));

#if defined(__has_builtin)
#if __has_builtin(__builtin_amdgcn_fdot2)
#define HAVE_FDOT2 1
#endif
#endif

static __device__ __forceinline__ unsigned ph2(float a, float b) {
    union { __half2 h; unsigned u; } c;
    c.h = __floats2half2_rn(a, b);
    return c.u;
}
static __device__ __forceinline__ h2v bch2(unsigned u) {
    union { unsigned u; h2v h; } c; c.u = u; return c.h;
}
static __device__ __forceinline__ float2 h2f2(unsigned u) {
    union { unsigned u; __half2 h; } c; c.u = u; return __half22float2(c.h);
}

// ---------------------------------------------------------------------------
// Setup: blocks 0..767 = inv_deg row sums; 768..771 = edge build for one
// 64-col wave group (coalesced, atomic-free, wave-uniform padded);
// 772 = routing softmax.
__global__ void k_setup(const float* __restrict__ adj,
                        const float* __restrict__ lrp,
                        float* __restrict__ inv_deg,
                        float* __restrict__ pol,
                        unsigned* __restrict__ epk,
                        int* __restrict__ gcnt) {
    const int b = blockIdx.x;
    const int tid = threadIdx.x;

    if (b < TT * NN) {
        __shared__ float wsum[4];
        float s = adj[(size_t)b * NN + tid];
#pragma unroll
        for (int off = 32; off > 0; off >>= 1) s += __shfl_down(s, off, 64);
        if ((tid & 63) == 0) wsum[tid >> 6] = s;
        __syncthreads();
        if (tid == 0)
            inv_deg[b] = 1.0f / fmaxf(wsum[0] + wsum[1] + wsum[2] + wsum[3], 1.0f);
    } else if (b < TT * NN + 4) {
        // edge lists for cols [64*grp, 64*grp+64): lane = col, coalesced j-scan
        __shared__ unsigned short offs[64][CAPE];   // 12 KB
        const int grp = b - TT * NN;
        if (tid < 64) {
            const int lane = tid;
            const int col = grp * 64 + lane;
            int cnt = 0;
#pragma unroll 4
            for (int j = 0; j < NN; j++) {
#pragma unroll
                for (int t = 0; t < TT; t++) {
                    float a = adj[((size_t)t * NN + j) * NN + col];
                    if (a != 0.f && cnt < CAPE)
                        offs[lane][cnt++] = (unsigned short)(j * ROWB + t * 8);
                }
            }
            int g = (cnt + 1) >> 1;
            int gmax = g;
#pragma unroll
            for (int off = 32; off > 0; off >>= 1) {
                int o = __shfl_xor(gmax, off, 64);
                gmax = o > gmax ? o : gmax;
            }
            for (int idx = cnt; idx < 2 * gmax; idx++)
                offs[lane][idx] = (unsigned short)ZROWB;
            for (int gg = 0; gg < gmax; gg++)
                epk[(size_t)gg * NN + col] =
                    (unsigned)offs[lane][2 * gg] | ((unsigned)offs[lane][2 * gg + 1] << 16);
            gcnt[col] = gmax;   // wave-uniform padded count
        }
    } else {
        if (tid < VV * NTY * SS) {
            float x[NAC]; float m = -3.4e38f;
#pragma unroll
            for (int a = 0; a < NAC; a++) { x[a] = lrp[tid * NAC + a]; m = fmaxf(m, x[a]); }
            float ssum = 0.f;
#pragma unroll
            for (int a = 0; a < NAC; a++) { x[a] = __expf(x[a] - m); ssum += x[a]; }
            float inv = 1.f / ssum;
#pragma unroll
            for (int a = 0; a < NAC; a++) pol[tid * NAC + a] = x[a] * inv;
        }
    }
}

// ---------------------------------------------------------------------------
// Main loop: grid 512 = (e,i); block 256 threads = one col each.
// Single barrier per step (parity-double-buffered tmp); edge list in VGPRs.
__global__ __launch_bounds__(256, 2) void k_main(
    const float* __restrict__ vw,
    const int* __restrict__ node_types,
    const float* __restrict__ pol,
    const float* __restrict__ inv_deg,
    const unsigned* __restrict__ epk,
    const int* __restrict__ gcnt,
    const int* __restrict__ steps_p,
    float* __restrict__ out)
{
    const int i    = blockIdx.x & 255;
    const int e    = blockIdx.x >> 8;
    const int col  = threadIdx.x;
    const int wv   = col >> 6;
    const int lane = col & 63;
    const int steps = steps_p[0];

    __shared__ __align__(16) char tmpb[2 * BUFB];   // 20.6 KB
    __shared__ float backp[2][4];

    if (col < 20) {
        int pb = col / 10, w = col % 10;
        ((unsigned*)(tmpb + pb * BUFB + ZROWB))[w] = 0u;
    }

    // --- per-col mixed policy, pre-scaled by inv_deg ---
    const float4 w4 = *(const float4*)(vw + ((size_t)i * NN + col) * VV);
    const float wvv[VV] = {w4.x, w4.y, w4.z, w4.w};
    const int ntj = node_types[col];
    float pmS[SS][12], pacc[SS], pback[SS];
#pragma unroll
    for (int s = 0; s < SS; s++) {
        pacc[s] = 0.f; pback[s] = 0.f;
#pragma unroll
        for (int a = 0; a < 12; a++) pmS[s][a] = 0.f;
    }
#pragma unroll
    for (int v = 0; v < VV; v++) {
        const float* pr = pol + (size_t)(v * NTY + ntj) * SS * NAC;
#pragma unroll
        for (int s = 0; s < SS; s++) {
            const float* p = pr + s * NAC;
#pragma unroll
            for (int a = 0; a < 12; a++) pmS[s][a] = fmaf(wvv[v], p[a], pmS[s][a]);
            pacc[s]  = fmaf(wvv[v], p[12], pacc[s]);
            pback[s] = fmaf(wvv[v], p[13], pback[s]);
        }
    }
    {
        float invd[TT];
#pragma unroll
        for (int t = 0; t < TT; t++) invd[t] = inv_deg[t * NN + col];
#pragma unroll
        for (int s = 0; s < SS; s++)
#pragma unroll
            for (int a = 0; a < 12; a++) pmS[s][a] *= invd[a >> 2];
    }

    float D0 = (0 == e && col == i) ? 1.f : 0.f;
    float D1 = (1 == e && col == i) ? 1.f : 0.f;
    float D2 = 0.f, D3 = 0.f;
    float acc = 0.f;

    // --- edge list into registers (step-invariant); gmax is wave-uniform ---
    const int gmax = __builtin_amdgcn_readfirstlane(gcnt[col]);
    unsigned ep[GMAXR];
#pragma unroll
    for (int g = 0; g < GMAXR; g++)
        ep[g] = (g < gmax) ? epk[(size_t)g * NN + col] : ZPK;

    const h2v S10 = {(_Float16)1.0f, (_Float16)0.0f};
    const h2v S01 = {(_Float16)0.0f, (_Float16)1.0f};
    char* const myrow0 = tmpb + col * ROWB;

    for (int step = 0; step < steps; step++) {
        const int par = step & 1;
        char* const buf = tmpb + par * BUFB;

        // ---- phase A: accept/back + scaled fp16 tmp row into buf[par] ----
        float ad = D0 * pacc[0];
        ad = fmaf(D1, pacc[1], ad); ad = fmaf(D2, pacc[2], ad); ad = fmaf(D3, pacc[3], ad);
        acc += ad;
        float bj = D0 * pback[0];
        bj = fmaf(D1, pback[1], bj); bj = fmaf(D2, pback[2], bj); bj = fmaf(D3, pback[3], bj);

        float tv[12];
#pragma unroll
        for (int a = 0; a < 12; a++) {
            float x = D0 * pmS[0][a];
            x = fmaf(D1, pmS[1][a], x);
            x = fmaf(D2, pmS[2][a], x);
            x = fmaf(D3, pmS[3][a], x);
            tv[a] = x;
        }
        char* const myrow = myrow0 + par * BUFB;
        uint2 wA; wA.x = ph2(tv[0], tv[1]);  wA.y = ph2(tv[2],  tv[3]);
        uint2 wB; wB.x = ph2(tv[4], tv[5]);  wB.y = ph2(tv[6],  tv[7]);
        uint2 wC; wC.x = ph2(tv[8], tv[9]);  wC.y = ph2(tv[10], tv[11]);
        *(uint2*)(myrow)      = wA;
        *(uint2*)(myrow + 8)  = wB;
        *(uint2*)(myrow + 16) = wC;

#pragma unroll
        for (int off = 32; off > 0; off >>= 1) bj += __shfl_down(bj, off, 64);
        if (lane == 0) backp[par][wv] = bj;

        __syncthreads();   // the ONLY barrier per step

        // ---- phase B: register-driven gather, dual accumulator sets ----
        float d0a = 0.f, d1a = 0.f, d2a = 0.f, d3a = 0.f;
        float d0b = 0.f, d1b = 0.f, d2b = 0.f, d3b = 0.f;
#pragma unroll
        for (int g = 0; g < GMAXR; g++) {
            if (g < gmax) {   // uniform (gmax in SGPR) -> scalar branch, no VALU
                const unsigned pk = ep[g];
                const uint2 q0 = *(const uint2*)(buf + (pk & 0xffffu));
                const uint2 q1 = *(const uint2*)(buf + (pk >> 16));
#ifdef HAVE_FDOT2
                if (g & 1) {
                    d0b = __builtin_amdgcn_fdot2(bch2(q0.x), S10, d0b, false);
                    d1b = __builtin_amdgcn_fdot2(bch2(q0.x), S01, d1b, false);
                    d2b = __builtin_amdgcn_fdot2(bch2(q0.y), S10, d2b, false);
                    d3b = __builtin_amdgcn_fdot2(bch2(q0.y), S01, d3b, false);
                    d0b = __builtin_amdgcn_fdot2(bch2(q1.x), S10, d0b, false);
                    d1b = __builtin_amdgcn_fdot2(bch2(q1.x), S01, d1b, false);
                    d2b = __builtin_amdgcn_fdot2(bch2(q1.y), S10, d2b, false);
                    d3b = __builtin_amdgcn_fdot2(bch2(q1.y), S01, d3b, false);
                } else {
                    d0a = __builtin_amdgcn_fdot2(bch2(q0.x), S10, d0a, false);
                    d1a = __builtin_amdgcn_fdot2(bch2(q0.x), S01, d1a, false);
                    d2a = __builtin_amdgcn_fdot2(bch2(q0.y), S10, d2a, false);
                    d3a = __builtin_amdgcn_fdot2(bch2(q0.y), S01, d3a, false);
                    d0a = __builtin_amdgcn_fdot2(bch2(q1.x), S10, d0a, false);
                    d1a = __builtin_amdgcn_fdot2(bch2(q1.x), S01, d1a, false);
                    d2a = __builtin_amdgcn_fdot2(bch2(q1.y), S10, d2a, false);
                    d3a = __builtin_amdgcn_fdot2(bch2(q1.y), S01, d3a, false);
                }
#else
                float2 f0 = h2f2(q0.x), f1 = h2f2(q0.y), f2 = h2f2(q1.x), f3 = h2f2(q1.y);
                if (g & 1) {
                    d0b += f0.x + f2.x; d1b += f0.y + f2.y;
                    d2b += f1.x + f3.x; d3b += f1.y + f3.y;
                } else {
                    d0a += f0.x + f2.x; d1a += f0.y + f2.y;
                    d2a += f1.x + f3.x; d3a += f1.y + f3.y;
                }
#endif
            }
        }
        // rare tail beyond register capacity (uniform bound, entries pre-padded)
        for (int g = GMAXR; g < gmax; g++) {
            const unsigned pk = epk[(size_t)g * NN + col];
            const uint2 q0 = *(const uint2*)(buf + (pk & 0xffffu));
            const uint2 q1 = *(const uint2*)(buf + (pk >> 16));
            float2 f0 = h2f2(q0.x), f1 = h2f2(q0.y), f2 = h2f2(q1.x), f3 = h2f2(q1.y);
            d0a += f0.x + f2.x; d1a += f0.y + f2.y;
            d2a += f1.x + f3.x; d3a += f1.y + f3.y;
        }

        float d0 = d0a + d0b, d1 = d1a + d1b, d2 = d2a + d2b, d3 = d3a + d3b;

        // ---- restart ----
        if (col == i) {
            const float* bp = backp[par];
            float back = bp[0] + bp[1] + bp[2] + bp[3];
            if (e == 0) d0 = fmaf(back, 0.999f, d0);
            else        d1 = fmaf(back, 0.999f, d1);
        }
        D0 = d0; D1 = d1; D2 = d2; D3 = d3;
    }

    float ad = D0 * pacc[0];
    ad = fmaf(D1, pacc[1], ad); ad = fmaf(D2, pacc[2], ad); ad = fmaf(D3, pacc[3], ad);
    acc += ad;
    out[((size_t)e * NN + i) * NN + col] = acc;
}

// ---------------------------------------------------------------------------
extern "C" void kernel_launch(void* const* d_in, const int* in_sizes, int n_in,
                              void* d_out, int out_size, void* d_ws, size_t ws_size,
                              hipStream_t stream) {
    const float* vw  = (const float*)d_in[0];   // (N,N,V) fp32
    const float* adj = (const float*)d_in[1];   // (T,N,N) fp32 {0,1}
    const float* lrp = (const float*)d_in[2];   // (V,NTY,S,NAC) fp32
    const int* node_types = (const int*)d_in[3];
    const int* steps_p    = (const int*)d_in[4];

    float* ws       = (float*)d_ws;
    float* pol      = ws;                        // 1920 f
    float* inv_deg  = ws + 1920;                 // 768 f
    int*   gcnt     = (int*)(ws + 2688);         // 256 i
    unsigned* epk   = (unsigned*)(ws + 2944);    // CAPG*NN u32 = 48 KB

    k_setup<<<TT * NN + 4 + 1, 256, 0, stream>>>(adj, lrp, inv_deg, pol, epk, gcnt);
    k_main<<<2 * NN, 256, 0, stream>>>(vw, node_types, pol, inv_deg, epk, gcnt,
                                       steps_p, (float*)d_out);
}

// Round 6
// 184.269 us; speedup vs baseline: 2.0536x; 2.0536x over previous
//
#include <hip/hip_runtime.h>
#include <hip/hip_fp16.h>

// Problem constants
#define NN    256   // NUM_NODES
#define SS    4     // NUM_FSM_STATES
#define TT    3     // NUM_EDGE_TYPES
#define VV    4     // NUM_VARIANTS
#define NTY   8     // NUM_NODE_TYPES
#define NAC   15    // n_actions = T*S + 3
#define CAPG  48    // max packed pair-groups per col (96 edges; deg~Poi(38.4))
#define CAPE  (CAPG * 2)
#define ROWB  40    // bytes per tmp row (12 halves used + pad)
#define ZROWB (NN * ROWB)       // zero pad row byte offset = 10240 (fits u16)
#define BUFB  (ZROWB + ROWB)    // bytes per tmp buffer
#define ZPK   ((unsigned)ZROWB | ((unsigned)ZROWB << 16))
#define GMAXR 32    // groups held in registers (covers wave-max ~27; tail via global)

typedef _Float16 h2v __attribute__((ext_vector_type(2)));

#if defined(__has_builtin)
#if __has_builtin(__builtin_amdgcn_fdot2)
#define HAVE_FDOT2 1
#endif
#endif

static __device__ __forceinline__ unsigned ph2(float a, float b) {
    union { __half2 h; unsigned u; } c;
    c.h = __floats2half2_rn(a, b);
    return c.u;
}
static __device__ __forceinline__ h2v bch2(unsigned u) {
    union { unsigned u; h2v h; } c; c.u = u; return c.h;
}
static __device__ __forceinline__ float2 h2f2(unsigned u) {
    union { unsigned u; __half2 h; } c; c.u = u; return __half22float2(c.h);
}

// ---------------------------------------------------------------------------
// Setup (fully parallel, round-4 proven structure):
//   blocks 0..767   : inv_deg row sums (coalesced, wave+LDS reduce)
//   blocks 768..1023: per-col edge build (LDS atomic compaction, order-free)
//   block  1024     : routing softmax
__global__ void k_setup(const float* __restrict__ adj,
                        const float* __restrict__ lrp,
                        float* __restrict__ inv_deg,
                        float* __restrict__ pol,
                        unsigned* __restrict__ epk,
                        int* __restrict__ gcnt) {
    const int b = blockIdx.x;
    const int tid = threadIdx.x;

    if (b < TT * NN) {
        __shared__ float wsum[4];
        float s = adj[(size_t)b * NN + tid];
#pragma unroll
        for (int off = 32; off > 0; off >>= 1) s += __shfl_down(s, off, 64);
        if ((tid & 63) == 0) wsum[tid >> 6] = s;
        __syncthreads();
        if (tid == 0)
            inv_deg[b] = 1.0f / fmaxf(wsum[0] + wsum[1] + wsum[2] + wsum[3], 1.0f);
    } else if (b < TT * NN + NN) {
        // edge list for column col: thread j tests (t,j,col), t=0..2
        __shared__ int cnt;
        __shared__ unsigned short offs[CAPE + 2];
        const int col = b - TT * NN;
        if (tid == 0) cnt = 0;
        __syncthreads();
#pragma unroll
        for (int t = 0; t < TT; t++) {
            float a = adj[((size_t)t * NN + tid) * NN + col];
            if (a != 0.f) {
                int idx = atomicAdd(&cnt, 1);
                if (idx < CAPE) offs[idx] = (unsigned short)(tid * ROWB + t * 8);
            }
        }
        __syncthreads();
        int c = cnt; if (c > CAPE) c = CAPE;
        if (tid == 0 && (c & 1)) offs[c] = (unsigned short)ZROWB;  // pad odd
        __syncthreads();
        const int g = (c + 1) >> 1;
        for (int gg = tid; gg < g; gg += blockDim.x)
            epk[(size_t)gg * NN + col] =
                (unsigned)offs[2 * gg] | ((unsigned)offs[2 * gg + 1] << 16);
        if (tid == 0) gcnt[col] = g;
    } else {
        if (tid < VV * NTY * SS) {
            float x[NAC]; float m = -3.4e38f;
#pragma unroll
            for (int a = 0; a < NAC; a++) { x[a] = lrp[tid * NAC + a]; m = fmaxf(m, x[a]); }
            float ssum = 0.f;
#pragma unroll
            for (int a = 0; a < NAC; a++) { x[a] = __expf(x[a] - m); ssum += x[a]; }
            float inv = 1.f / ssum;
#pragma unroll
            for (int a = 0; a < NAC; a++) pol[tid * NAC + a] = x[a] * inv;
        }
    }
}

// ---------------------------------------------------------------------------
// Main loop: grid 512 = (e,i); block 256 threads = one col each.
// Single barrier per step (parity-double-buffered tmp); edge list in VGPRs;
// wave-uniform gather trip via shuffle-max + readfirstlane.
__global__ __launch_bounds__(256, 2) void k_main(
    const float* __restrict__ vw,
    const int* __restrict__ node_types,
    const float* __restrict__ pol,
    const float* __restrict__ inv_deg,
    const unsigned* __restrict__ epk,
    const int* __restrict__ gcnt,
    const int* __restrict__ steps_p,
    float* __restrict__ out)
{
    const int i    = blockIdx.x & 255;
    const int e    = blockIdx.x >> 8;
    const int col  = threadIdx.x;
    const int wv   = col >> 6;
    const int lane = col & 63;
    const int steps = steps_p[0];

    __shared__ __align__(16) char tmpb[2 * BUFB];   // 20.6 KB
    __shared__ float backp[2][4];

    if (col < 20) {
        int pb = col / 10, w = col % 10;
        ((unsigned*)(tmpb + pb * BUFB + ZROWB))[w] = 0u;
    }

    // --- per-col mixed policy, pre-scaled by inv_deg ---
    const float4 w4 = *(const float4*)(vw + ((size_t)i * NN + col) * VV);
    const float wvv[VV] = {w4.x, w4.y, w4.z, w4.w};
    const int ntj = node_types[col];
    float pmS[SS][12], pacc[SS], pback[SS];
#pragma unroll
    for (int s = 0; s < SS; s++) {
        pacc[s] = 0.f; pback[s] = 0.f;
#pragma unroll
        for (int a = 0; a < 12; a++) pmS[s][a] = 0.f;
    }
#pragma unroll
    for (int v = 0; v < VV; v++) {
        const float* pr = pol + (size_t)(v * NTY + ntj) * SS * NAC;
#pragma unroll
        for (int s = 0; s < SS; s++) {
            const float* p = pr + s * NAC;
#pragma unroll
            for (int a = 0; a < 12; a++) pmS[s][a] = fmaf(wvv[v], p[a], pmS[s][a]);
            pacc[s]  = fmaf(wvv[v], p[12], pacc[s]);
            pback[s] = fmaf(wvv[v], p[13], pback[s]);
        }
    }
    {
        float invd[TT];
#pragma unroll
        for (int t = 0; t < TT; t++) invd[t] = inv_deg[t * NN + col];
#pragma unroll
        for (int s = 0; s < SS; s++)
#pragma unroll
            for (int a = 0; a < 12; a++) pmS[s][a] *= invd[a >> 2];
    }

    float D0 = (0 == e && col == i) ? 1.f : 0.f;
    float D1 = (1 == e && col == i) ? 1.f : 0.f;
    float D2 = 0.f, D3 = 0.f;
    float acc = 0.f;

    // --- edge list into registers (step-invariant) ---
    const int g_all = gcnt[col];
    int gm = g_all;
#pragma unroll
    for (int off = 32; off > 0; off >>= 1) {
        int o = __shfl_xor(gm, off, 64);
        gm = o > gm ? o : gm;
    }
    const int gmax = __builtin_amdgcn_readfirstlane(gm);   // wave-uniform

    unsigned ep[GMAXR];
#pragma unroll
    for (int g = 0; g < GMAXR; g++) {
        unsigned pk = epk[(size_t)g * NN + col];   // in-bounds; junk past g_all
        ep[g] = (g < g_all) ? pk : ZPK;            // junk never dereferenced
    }

    const h2v S10 = {(_Float16)1.0f, (_Float16)0.0f};
    const h2v S01 = {(_Float16)0.0f, (_Float16)1.0f};
    char* const myrow0 = tmpb + col * ROWB;

    for (int step = 0; step < steps; step++) {
        const int par = step & 1;
        char* const buf = tmpb + par * BUFB;

        // ---- phase A: accept/back + scaled fp16 tmp row into buf[par] ----
        float ad = D0 * pacc[0];
        ad = fmaf(D1, pacc[1], ad); ad = fmaf(D2, pacc[2], ad); ad = fmaf(D3, pacc[3], ad);
        acc += ad;
        float bj = D0 * pback[0];
        bj = fmaf(D1, pback[1], bj); bj = fmaf(D2, pback[2], bj); bj = fmaf(D3, pback[3], bj);

        float tv[12];
#pragma unroll
        for (int a = 0; a < 12; a++) {
            float x = D0 * pmS[0][a];
            x = fmaf(D1, pmS[1][a], x);
            x = fmaf(D2, pmS[2][a], x);
            x = fmaf(D3, pmS[3][a], x);
            tv[a] = x;
        }
        char* const myrow = myrow0 + par * BUFB;
        uint2 wA; wA.x = ph2(tv[0], tv[1]);  wA.y = ph2(tv[2],  tv[3]);
        uint2 wB; wB.x = ph2(tv[4], tv[5]);  wB.y = ph2(tv[6],  tv[7]);
        uint2 wC; wC.x = ph2(tv[8], tv[9]);  wC.y = ph2(tv[10], tv[11]);
        *(uint2*)(myrow)      = wA;
        *(uint2*)(myrow + 8)  = wB;
        *(uint2*)(myrow + 16) = wC;

#pragma unroll
        for (int off = 32; off > 0; off >>= 1) bj += __shfl_down(bj, off, 64);
        if (lane == 0) backp[par][wv] = bj;

        __syncthreads();   // the ONLY barrier per step

        // ---- phase B: register-driven gather, dual accumulator sets ----
        float d0a = 0.f, d1a = 0.f, d2a = 0.f, d3a = 0.f;
        float d0b = 0.f, d1b = 0.f, d2b = 0.f, d3b = 0.f;
#pragma unroll
        for (int g = 0; g < GMAXR; g++) {
            if (g < gmax) {   // gmax in SGPR -> scalar branch, no VALU
                const unsigned pk = ep[g];
                const uint2 q0 = *(const uint2*)(buf + (pk & 0xffffu));
                const uint2 q1 = *(const uint2*)(buf + (pk >> 16));
#ifdef HAVE_FDOT2
                if (g & 1) {
                    d0b = __builtin_amdgcn_fdot2(bch2(q0.x), S10, d0b, false);
                    d1b = __builtin_amdgcn_fdot2(bch2(q0.x), S01, d1b, false);
                    d2b = __builtin_amdgcn_fdot2(bch2(q0.y), S10, d2b, false);
                    d3b = __builtin_amdgcn_fdot2(bch2(q0.y), S01, d3b, false);
                    d0b = __builtin_amdgcn_fdot2(bch2(q1.x), S10, d0b, false);
                    d1b = __builtin_amdgcn_fdot2(bch2(q1.x), S01, d1b, false);
                    d2b = __builtin_amdgcn_fdot2(bch2(q1.y), S10, d2b, false);
                    d3b = __builtin_amdgcn_fdot2(bch2(q1.y), S01, d3b, false);
                } else {
                    d0a = __builtin_amdgcn_fdot2(bch2(q0.x), S10, d0a, false);
                    d1a = __builtin_amdgcn_fdot2(bch2(q0.x), S01, d1a, false);
                    d2a = __builtin_amdgcn_fdot2(bch2(q0.y), S10, d2a, false);
                    d3a = __builtin_amdgcn_fdot2(bch2(q0.y), S01, d3a, false);
                    d0a = __builtin_amdgcn_fdot2(bch2(q1.x), S10, d0a, false);
                    d1a = __builtin_amdgcn_fdot2(bch2(q1.x), S01, d1a, false);
                    d2a = __builtin_amdgcn_fdot2(bch2(q1.y), S10, d2a, false);
                    d3a = __builtin_amdgcn_fdot2(bch2(q1.y), S01, d3a, false);
                }
#else
                float2 f0 = h2f2(q0.x), f1 = h2f2(q0.y), f2 = h2f2(q1.x), f3 = h2f2(q1.y);
                if (g & 1) {
                    d0b += f0.x + f2.x; d1b += f0.y + f2.y;
                    d2b += f1.x + f3.x; d3b += f1.y + f3.y;
                } else {
                    d0a += f0.x + f2.x; d1a += f0.y + f2.y;
                    d2a += f1.x + f3.x; d3a += f1.y + f3.y;
                }
#endif
            }
        }
        // rare tail beyond register capacity (per-lane guard vs junk entries)
        for (int g = GMAXR; g < gmax; g++) {
            unsigned pk = epk[(size_t)g * NN + col];
            pk = (g < g_all) ? pk : ZPK;
            const uint2 q0 = *(const uint2*)(buf + (pk & 0xffffu));
            const uint2 q1 = *(const uint2*)(buf + (pk >> 16));
            float2 f0 = h2f2(q0.x), f1 = h2f2(q0.y), f2 = h2f2(q1.x), f3 = h2f2(q1.y);
            d0a += f0.x + f2.x; d1a += f0.y + f2.y;
            d2a += f1.x + f3.x; d3a += f1.y + f3.y;
        }

        float d0 = d0a + d0b, d1 = d1a + d1b, d2 = d2a + d2b, d3 = d3a + d3b;

        // ---- restart ----
        if (col == i) {
            const float* bp = backp[par];
            float back = bp[0] + bp[1] + bp[2] + bp[3];
            if (e == 0) d0 = fmaf(back, 0.999f, d0);
            else        d1 = fmaf(back, 0.999f, d1);
        }
        D0 = d0; D1 = d1; D2 = d2; D3 = d3;
    }

    float ad = D0 * pacc[0];
    ad = fmaf(D1, pacc[1], ad); ad = fmaf(D2, pacc[2], ad); ad = fmaf(D3, pacc[3], ad);
    acc += ad;
    out[((size_t)e * NN + i) * NN + col] = acc;
}

// ---------------------------------------------------------------------------
extern "C" void kernel_launch(void* const* d_in, const int* in_sizes, int n_in,
                              void* d_out, int out_size, void* d_ws, size_t ws_size,
                              hipStream_t stream) {
    const float* vw  = (const float*)d_in[0];   // (N,N,V) fp32
    const float* adj = (const float*)d_in[1];   // (T,N,N) fp32 {0,1}
    const float* lrp = (const float*)d_in[2];   // (V,NTY,S,NAC) fp32
    const int* node_types = (const int*)d_in[3];
    const int* steps_p    = (const int*)d_in[4];

    float* ws       = (float*)d_ws;
    float* pol      = ws;                        // 1920 f
    float* inv_deg  = ws + 1920;                 // 768 f
    int*   gcnt     = (int*)(ws + 2688);         // 256 i
    unsigned* epk   = (unsigned*)(ws + 2944);    // CAPG*NN u32 = 48 KB

    k_setup<<<TT * NN + NN + 1, 256, 0, stream>>>(adj, lrp, inv_deg, pol, epk, gcnt);
    k_main<<<2 * NN, 256, 0, stream>>>(vw, node_types, pol, inv_deg, epk, gcnt,
                                       steps_p, (float*)d_out);
}